// Round 1
// baseline (1762.861 us; speedup 1.0000x reference)
//
#include <hip/hip_runtime.h>
#include <cstdint>
#include <cstddef>

#define NPOINT 1024
#define NSAMPLE 32
#define BATCH 8
#define NPTS 4096
#define DFEAT 64
#define CIN 67
#define C1 64
#define C2 64
#define C3 128
#define BN_EPS 1e-5f

// ---------------------------------------------------------------------------
// FPS: one block per batch. Bit-exact distance math (no FMA contraction),
// argmax with first-index tie-break to match jnp.argmax.
// ---------------------------------------------------------------------------
__global__ __launch_bounds__(512) void fps_kernel(const float* __restrict__ xyz,
                                                  float* __restrict__ dout) {
    const int b = blockIdx.x;
    const float* xb = xyz + (size_t)b * 3 * NPTS;
    float* ox = dout + (size_t)b * 3 * NPOINT;

    __shared__ float sx[NPTS], sy[NPTS], sz[NPTS];
    __shared__ float redv[8];
    __shared__ int   redi[8];

    const int t = threadIdx.x;
    for (int j = t; j < NPTS; j += 512) {
        sx[j] = xb[j];
        sy[j] = xb[NPTS + j];
        sz[j] = xb[2 * NPTS + j];
    }
    __syncthreads();

    constexpr int PT = NPTS / 512;  // 8 points per thread
    float px[PT], py[PT], pz[PT], dist[PT];
    const int base = t * PT;
#pragma unroll
    for (int u = 0; u < PT; ++u) {
        px[u] = sx[base + u];
        py[u] = sy[base + u];
        pz[u] = sz[base + u];
        dist[u] = 1e10f;
    }

    int last = 0;
    if (t == 0) {
        ox[0] = sx[0];
        ox[NPOINT] = sy[0];
        ox[2 * NPOINT] = sz[0];
    }

    for (int s = 1; s < NPOINT; ++s) {
        const float cx = sx[last], cy = sy[last], cz = sz[last];
        float bv = -1.0f;
        int bi = 0x7fffffff;
#pragma unroll
        for (int u = 0; u < PT; ++u) {
            float dx = __fsub_rn(px[u], cx);
            float dy = __fsub_rn(py[u], cy);
            float dz = __fsub_rn(pz[u], cz);
            float d = __fadd_rn(__fadd_rn(__fmul_rn(dx, dx), __fmul_rn(dy, dy)),
                                __fmul_rn(dz, dz));
            float nd = fminf(dist[u], d);
            dist[u] = nd;
            if (nd > bv) { bv = nd; bi = base + u; }  // ascending scan keeps first max
        }
        // 64-lane butterfly argmax, tie -> smaller index
#pragma unroll
        for (int m = 32; m >= 1; m >>= 1) {
            float ov = __shfl_xor(bv, m, 64);
            int oi = __shfl_xor(bi, m, 64);
            if (ov > bv || (ov == bv && oi < bi)) { bv = ov; bi = oi; }
        }
        const int wv = t >> 6;
        if ((t & 63) == 0) { redv[wv] = bv; redi[wv] = bi; }
        __syncthreads();
        float gv = redv[0];
        int gi = redi[0];
#pragma unroll
        for (int w = 1; w < 8; ++w) {
            float v = redv[w];
            int i2 = redi[w];
            if (v > gv || (v == gv && i2 < gi)) { gv = v; gi = i2; }
        }
        last = gi;
        if (t == 0) {
            ox[s] = sx[last];
            ox[NPOINT + s] = sy[last];
            ox[2 * NPOINT + s] = sz[last];
        }
        __syncthreads();
    }
}

// ---------------------------------------------------------------------------
// Transpose points (B,64,N) -> (B,N,64) so MLP gathers are contiguous.
// ---------------------------------------------------------------------------
__global__ __launch_bounds__(256) void transpose_pts(const float* __restrict__ pts,
                                                     float* __restrict__ ptsT) {
    __shared__ float tile[64][65];
    const int b = blockIdx.x / (NPTS / 64);
    const int n0 = (blockIdx.x % (NPTS / 64)) * 64;
    const int t = threadIdx.x;
    const int nl = t & 63, cq = t >> 6;
    const float* pb = pts + (size_t)b * DFEAT * NPTS;
#pragma unroll
    for (int i = 0; i < 16; ++i) {
        int c = i * 4 + cq;
        tile[c][nl] = pb[(size_t)c * NPTS + n0 + nl];
    }
    __syncthreads();
    float* ob = ptsT + (size_t)b * NPTS * DFEAT;
    const int cl = t & 63, nq = t >> 6;
#pragma unroll
    for (int i = 0; i < 16; ++i) {
        int n = i * 4 + nq;
        ob[(size_t)(n0 + n) * DFEAT + cl] = tile[cl][n];
    }
}

// ---------------------------------------------------------------------------
// Ball query: one wave per query point. First 32 ascending indices with
// d2 <= r2, padded with the first. Bit-exact d2.
// ---------------------------------------------------------------------------
__global__ __launch_bounds__(256) void ballquery_kernel(const float* __restrict__ xyz,
                                                        const float* __restrict__ dout,
                                                        int* __restrict__ idx) {
    const int wv = threadIdx.x >> 6, lane = threadIdx.x & 63;
    const int sg = blockIdx.x * 4 + wv;  // b*NPOINT + s
    const int b = sg / NPOINT, s = sg % NPOINT;
    const float* xb = xyz + (size_t)b * 3 * NPTS;
    const float* nx = dout + (size_t)b * 3 * NPOINT;
    const float cx = nx[s], cy = nx[NPOINT + s], cz = nx[2 * NPOINT + s];
    int* ob = idx + (size_t)sg * NSAMPLE;
    const float r2 = 0.04f;  // f32(0.2*0.2)

    int cnt = 0;
    int first = -1;
    for (int tch = 0; tch < NPTS / 64 && cnt < NSAMPLE; ++tch) {
        const int j = tch * 64 + lane;
        float dx = __fsub_rn(cx, xb[j]);
        float dy = __fsub_rn(cy, xb[NPTS + j]);
        float dz = __fsub_rn(cz, xb[2 * NPTS + j]);
        float d2 = __fadd_rn(__fadd_rn(__fmul_rn(dx, dx), __fmul_rn(dy, dy)),
                             __fmul_rn(dz, dz));
        unsigned long long mask = __ballot(d2 <= r2);
        while (mask && cnt < NSAMPLE) {
            int bit = __builtin_ctzll(mask);
            int pj = tch * 64 + bit;
            if (cnt == 0) first = pj;
            if (lane == 0) ob[cnt] = pj;
            cnt++;
            mask &= mask - 1;
        }
    }
    if (lane == 0) {
        for (int r = cnt; r < NSAMPLE; ++r) ob[r] = first;
    }
}

// ---------------------------------------------------------------------------
// Fused group + 3x conv-BN-ReLU + max over nsample.
// Thread = one (s,k) column. Inputs in registers; weights via wave-uniform
// (scalar) loads; activations bounce through LDS [64][256] (conflict-free).
// ---------------------------------------------------------------------------
template <int TRANSPOSED>
__global__ __launch_bounds__(256) void mlp_kernel(
    const float* __restrict__ xyz, const float* __restrict__ pts,
    const int* __restrict__ idx, const float* __restrict__ dnew,
    const float* __restrict__ w0, const float* __restrict__ b0,
    const float* __restrict__ g0, const float* __restrict__ bt0,
    const float* __restrict__ rm0, const float* __restrict__ rv0,
    const float* __restrict__ w1, const float* __restrict__ b1,
    const float* __restrict__ g1, const float* __restrict__ bt1,
    const float* __restrict__ rm1, const float* __restrict__ rv1,
    const float* __restrict__ w2, const float* __restrict__ b2,
    const float* __restrict__ g2, const float* __restrict__ bt2,
    const float* __restrict__ rm2, const float* __restrict__ rv2,
    float* __restrict__ outf) {
    __shared__ float ylds[64][256];
    const int t = threadIdx.x;
    const int k = t & 31, sl = t >> 5;
    const int b = blockIdx.x >> 7;
    const int s = (blockIdx.x & 127) * 8 + sl;
    const int p = idx[((size_t)(b * NPOINT + s)) * NSAMPLE + k];

    const float* xb = xyz + (size_t)b * 3 * NPTS;
    const float* nx = dnew + (size_t)b * 3 * NPOINT;

    float x[CIN];
    x[0] = xb[p] - nx[s];
    x[1] = xb[NPTS + p] - nx[NPOINT + s];
    x[2] = xb[2 * NPTS + p] - nx[2 * NPOINT + s];
    if (TRANSPOSED) {
        const float* pb = pts + ((size_t)b * NPTS + p) * DFEAT;
#pragma unroll
        for (int c = 0; c < DFEAT; ++c) x[3 + c] = pb[c];
    } else {
        const float* pb = pts + (size_t)b * DFEAT * NPTS + p;
#pragma unroll
        for (int c = 0; c < DFEAT; ++c) x[3 + c] = pb[(size_t)c * NPTS];
    }

    // layer 1: 67 -> 64
    for (int o = 0; o < C1; ++o) {
        float acc = 0.f;
#pragma unroll
        for (int c = 0; c < CIN; ++c) acc = fmaf(w0[o * CIN + c], x[c], acc);
        float sc = g0[o] * rsqrtf(rv0[o] + BN_EPS);
        float y = fmaf(sc, acc + b0[o] - rm0[o], bt0[o]);
        ylds[o][t] = fmaxf(y, 0.f);
    }
    __syncthreads();
    float x1[C1];
#pragma unroll
    for (int c = 0; c < C1; ++c) x1[c] = ylds[c][t];
    __syncthreads();

    // layer 2: 64 -> 64
    for (int o = 0; o < C2; ++o) {
        float acc = 0.f;
#pragma unroll
        for (int c = 0; c < C1; ++c) acc = fmaf(w1[o * C1 + c], x1[c], acc);
        float sc = g1[o] * rsqrtf(rv1[o] + BN_EPS);
        float y = fmaf(sc, acc + b1[o] - rm1[o], bt1[o]);
        ylds[o][t] = fmaxf(y, 0.f);
    }
    __syncthreads();
    float x2[C2];
#pragma unroll
    for (int c = 0; c < C2; ++c) x2[c] = ylds[c][t];

    // layer 3: 64 -> 128, then max over k (32 lanes sharing s)
    float* ob = outf + (size_t)b * C3 * NPOINT;
    for (int o = 0; o < C3; ++o) {
        float acc = 0.f;
#pragma unroll
        for (int c = 0; c < C2; ++c) acc = fmaf(w2[o * C2 + c], x2[c], acc);
        float sc = g2[o] * rsqrtf(rv2[o] + BN_EPS);
        float y = fmaf(sc, acc + b2[o] - rm2[o], bt2[o]);
        float v = fmaxf(y, 0.f);
#pragma unroll
        for (int m = 16; m >= 1; m >>= 1) v = fmaxf(v, __shfl_xor(v, m, 32));
        if (k == 0) ob[(size_t)o * NPOINT + s] = v;
    }
}

// ---------------------------------------------------------------------------
extern "C" void kernel_launch(void* const* d_in, const int* in_sizes, int n_in,
                              void* d_out, int out_size, void* d_ws, size_t ws_size,
                              hipStream_t stream) {
    const float* xyz = (const float*)d_in[0];
    const float* pts = (const float*)d_in[1];
    const float* w0 = (const float*)d_in[2];
    const float* b0 = (const float*)d_in[3];
    const float* g0 = (const float*)d_in[4];
    const float* bt0 = (const float*)d_in[5];
    const float* rm0 = (const float*)d_in[6];
    const float* rv0 = (const float*)d_in[7];
    const float* w1 = (const float*)d_in[8];
    const float* b1 = (const float*)d_in[9];
    const float* g1 = (const float*)d_in[10];
    const float* bt1 = (const float*)d_in[11];
    const float* rm1 = (const float*)d_in[12];
    const float* rv1 = (const float*)d_in[13];
    const float* w2 = (const float*)d_in[14];
    const float* b2 = (const float*)d_in[15];
    const float* g2 = (const float*)d_in[16];
    const float* bt2 = (const float*)d_in[17];
    const float* rm2 = (const float*)d_in[18];
    const float* rv2 = (const float*)d_in[19];

    float* out = (float*)d_out;
    float* outf = out + (size_t)BATCH * 3 * NPOINT;

    const size_t idx_bytes = (size_t)BATCH * NPOINT * NSAMPLE * sizeof(int);  // 1 MB
    const size_t idx_pad = (idx_bytes + 255) & ~(size_t)255;
    const size_t ptsT_bytes = (size_t)BATCH * NPTS * DFEAT * sizeof(float);   // 8 MB
    int* idx = (int*)d_ws;
    float* ptsT = (float*)((char*)d_ws + idx_pad);
    const bool useT = ws_size >= idx_pad + ptsT_bytes;

    fps_kernel<<<BATCH, 512, 0, stream>>>(xyz, out);
    if (useT) transpose_pts<<<BATCH * (NPTS / 64), 256, 0, stream>>>(pts, ptsT);
    ballquery_kernel<<<BATCH * NPOINT / 4, 256, 0, stream>>>(xyz, out, idx);
    if (useT) {
        mlp_kernel<1><<<BATCH * NPOINT / 8, 256, 0, stream>>>(
            xyz, ptsT, idx, out, w0, b0, g0, bt0, rm0, rv0, w1, b1, g1, bt1, rm1,
            rv1, w2, b2, g2, bt2, rm2, rv2, outf);
    } else {
        mlp_kernel<0><<<BATCH * NPOINT / 8, 256, 0, stream>>>(
            xyz, pts, idx, out, w0, b0, g0, bt0, rm0, rv0, w1, b1, g1, bt1, rm1,
            rv1, w2, b2, g2, bt2, rm2, rv2, outf);
    }
}

// Round 2
// 966.729 us; speedup vs baseline: 1.8235x; 1.8235x over previous
//
#include <hip/hip_runtime.h>
#include <cstdint>
#include <cstddef>

#define NPOINT 1024
#define NSAMPLE 32
#define BATCH 8
#define NPTS 4096
#define DFEAT 64
#define CIN 67
#define C1 64
#define C2 64
#define C3 128
#define BN_EPS 1e-5f

// ---------------------------------------------------------------------------
// FPS: one block per batch. Bit-exact distance math (no FMA contraction),
// argmax with first-index tie-break to match jnp.argmax.
// Latency-optimized: DPP wave-max, ballot index pick, single barrier/step.
// ---------------------------------------------------------------------------
__device__ __forceinline__ float wave64_max_bcast(float v) {
    // values must be >= 0 (bound_ctrl zero-fill loses). Result valid in lane 63,
    // broadcast via readlane.
    int x;
    x = __builtin_amdgcn_update_dpp(0, __float_as_int(v), 0x111, 0xf, 0xf, true);
    v = fmaxf(v, __int_as_float(x));  // row_shr:1
    x = __builtin_amdgcn_update_dpp(0, __float_as_int(v), 0x112, 0xf, 0xf, true);
    v = fmaxf(v, __int_as_float(x));  // row_shr:2
    x = __builtin_amdgcn_update_dpp(0, __float_as_int(v), 0x114, 0xf, 0xf, true);
    v = fmaxf(v, __int_as_float(x));  // row_shr:4
    x = __builtin_amdgcn_update_dpp(0, __float_as_int(v), 0x118, 0xf, 0xf, true);
    v = fmaxf(v, __int_as_float(x));  // row_shr:8
    x = __builtin_amdgcn_update_dpp(0, __float_as_int(v), 0x142, 0xf, 0xf, true);
    v = fmaxf(v, __int_as_float(x));  // row_bcast:15
    x = __builtin_amdgcn_update_dpp(0, __float_as_int(v), 0x143, 0xf, 0xf, true);
    v = fmaxf(v, __int_as_float(x));  // row_bcast:31
    return __int_as_float(__builtin_amdgcn_readlane(__float_as_int(v), 63));
}

__global__ __launch_bounds__(512) void fps_kernel(const float* __restrict__ xyz,
                                                  float* __restrict__ dout) {
    const int b = blockIdx.x;
    const float* xb = xyz + (size_t)b * 3 * NPTS;
    float* ox = dout + (size_t)b * 3 * NPOINT;

    __shared__ float sx[NPTS], sy[NPTS], sz[NPTS];
    __shared__ unsigned long long redk[2][8];

    const int t = threadIdx.x;
    for (int j = t; j < NPTS; j += 512) {
        sx[j] = xb[j];
        sy[j] = xb[NPTS + j];
        sz[j] = xb[2 * NPTS + j];
    }
    __syncthreads();

    constexpr int PT = NPTS / 512;  // 8 points per thread, contiguous block
    float px[PT], py[PT], pz[PT], dist[PT];
    const int base = t * PT;
#pragma unroll
    for (int u = 0; u < PT; ++u) {
        px[u] = sx[base + u];
        py[u] = sy[base + u];
        pz[u] = sz[base + u];
        dist[u] = 1e10f;
    }

    int last = 0;
    if (t == 0) {
        ox[0] = sx[0];
        ox[NPOINT] = sy[0];
        ox[2 * NPOINT] = sz[0];
    }

    for (int s = 1; s < NPOINT; ++s) {
        const float cx = sx[last], cy = sy[last], cz = sz[last];
        float bv = 0.0f;
#pragma unroll
        for (int u = 0; u < PT; ++u) {
            float dx = __fsub_rn(px[u], cx);
            float dy = __fsub_rn(py[u], cy);
            float dz = __fsub_rn(pz[u], cz);
            float d = __fadd_rn(__fadd_rn(__fmul_rn(dx, dx), __fmul_rn(dy, dy)),
                                __fmul_rn(dz, dz));
            float nd = fminf(dist[u], d);
            dist[u] = nd;
            bv = fmaxf(bv, nd);
        }
        // wave-level max (DPP, VALU-pipe) then recover first matching index
        const float wmax = wave64_max_bcast(bv);
        int li = 0;
        if (bv == wmax) {
#pragma unroll
            for (int u = PT - 1; u >= 0; --u)
                if (dist[u] == wmax) li = base + u;  // descending -> keeps smallest
        }
        const unsigned long long m = __ballot(bv == wmax);
        const int fl = __ffsll(m) - 1;  // first matching lane = smallest indices
        const int wbi = __builtin_amdgcn_readlane(li, fl);

        const int wv = t >> 6;
        if ((t & 63) == 0) {
            redk[s & 1][wv] =
                ((unsigned long long)__float_as_uint(wmax) << 32) |
                (unsigned)(0xFFFFFFFFu - (unsigned)wbi);
        }
        __syncthreads();
        unsigned long long gk = redk[s & 1][0];
#pragma unroll
        for (int w = 1; w < 8; ++w) {
            unsigned long long k2 = redk[s & 1][w];
            if (k2 > gk) gk = k2;
        }
        last = (int)(0xFFFFFFFFu - (unsigned)(gk & 0xFFFFFFFFull));
        if (t == 0) {
            ox[s] = sx[last];
            ox[NPOINT + s] = sy[last];
            ox[2 * NPOINT + s] = sz[last];
        }
    }
}

// ---------------------------------------------------------------------------
// Transpose points (B,64,N) -> (B,N,64) so MLP gathers are contiguous.
// ---------------------------------------------------------------------------
__global__ __launch_bounds__(256) void transpose_pts(const float* __restrict__ pts,
                                                     float* __restrict__ ptsT) {
    __shared__ float tile[64][65];
    const int b = blockIdx.x / (NPTS / 64);
    const int n0 = (blockIdx.x % (NPTS / 64)) * 64;
    const int t = threadIdx.x;
    const int nl = t & 63, cq = t >> 6;
    const float* pb = pts + (size_t)b * DFEAT * NPTS;
#pragma unroll
    for (int i = 0; i < 16; ++i) {
        int c = i * 4 + cq;
        tile[c][nl] = pb[(size_t)c * NPTS + n0 + nl];
    }
    __syncthreads();
    float* ob = ptsT + (size_t)b * NPTS * DFEAT;
    const int cl = t & 63, nq = t >> 6;
#pragma unroll
    for (int i = 0; i < 16; ++i) {
        int n = i * 4 + nq;
        ob[(size_t)(n0 + n) * DFEAT + cl] = tile[cl][n];
    }
}

// ---------------------------------------------------------------------------
// Ball query: one wave per query point. First 32 ascending indices with
// d2 <= r2, padded with the first. Bit-exact d2.
// ---------------------------------------------------------------------------
__global__ __launch_bounds__(256) void ballquery_kernel(const float* __restrict__ xyz,
                                                        const float* __restrict__ dout,
                                                        int* __restrict__ idx) {
    const int wv = threadIdx.x >> 6, lane = threadIdx.x & 63;
    const int sg = blockIdx.x * 4 + wv;  // b*NPOINT + s
    const int b = sg / NPOINT, s = sg % NPOINT;
    const float* xb = xyz + (size_t)b * 3 * NPTS;
    const float* nx = dout + (size_t)b * 3 * NPOINT;
    const float cx = nx[s], cy = nx[NPOINT + s], cz = nx[2 * NPOINT + s];
    int* ob = idx + (size_t)sg * NSAMPLE;
    const float r2 = 0.04f;  // f32(0.2*0.2)

    int cnt = 0;
    int first = -1;
    for (int tch = 0; tch < NPTS / 64 && cnt < NSAMPLE; ++tch) {
        const int j = tch * 64 + lane;
        float dx = __fsub_rn(cx, xb[j]);
        float dy = __fsub_rn(cy, xb[NPTS + j]);
        float dz = __fsub_rn(cz, xb[2 * NPTS + j]);
        float d2 = __fadd_rn(__fadd_rn(__fmul_rn(dx, dx), __fmul_rn(dy, dy)),
                             __fmul_rn(dz, dz));
        unsigned long long mask = __ballot(d2 <= r2);
        while (mask && cnt < NSAMPLE) {
            int bit = __builtin_ctzll(mask);
            int pj = tch * 64 + bit;
            if (cnt == 0) first = pj;
            if (lane == 0) ob[cnt] = pj;
            cnt++;
            mask &= mask - 1;
        }
    }
    if (lane == 0) {
        for (int r = cnt; r < NSAMPLE; ++r) ob[r] = first;
    }
}

// ---------------------------------------------------------------------------
// Fused group + 3x conv-BN-ReLU + max over nsample.
// Thread = one (s,k) column. Inputs in registers; weights via wave-uniform
// (scalar) loads; activations bounce through LDS [64][256] (conflict-free).
// ---------------------------------------------------------------------------
template <int TRANSPOSED>
__global__ __launch_bounds__(256) void mlp_kernel(
    const float* __restrict__ xyz, const float* __restrict__ pts,
    const int* __restrict__ idx, const float* __restrict__ dnew,
    const float* __restrict__ w0, const float* __restrict__ b0,
    const float* __restrict__ g0, const float* __restrict__ bt0,
    const float* __restrict__ rm0, const float* __restrict__ rv0,
    const float* __restrict__ w1, const float* __restrict__ b1,
    const float* __restrict__ g1, const float* __restrict__ bt1,
    const float* __restrict__ rm1, const float* __restrict__ rv1,
    const float* __restrict__ w2, const float* __restrict__ b2,
    const float* __restrict__ g2, const float* __restrict__ bt2,
    const float* __restrict__ rm2, const float* __restrict__ rv2,
    float* __restrict__ outf) {
    __shared__ float ylds[64][256];
    const int t = threadIdx.x;
    const int k = t & 31, sl = t >> 5;
    const int b = blockIdx.x >> 7;
    const int s = (blockIdx.x & 127) * 8 + sl;
    const int p = idx[((size_t)(b * NPOINT + s)) * NSAMPLE + k];

    const float* xb = xyz + (size_t)b * 3 * NPTS;
    const float* nx = dnew + (size_t)b * 3 * NPOINT;

    float x[CIN];
    x[0] = xb[p] - nx[s];
    x[1] = xb[NPTS + p] - nx[NPOINT + s];
    x[2] = xb[2 * NPTS + p] - nx[2 * NPOINT + s];
    if (TRANSPOSED) {
        const float* pb = pts + ((size_t)b * NPTS + p) * DFEAT;
#pragma unroll
        for (int c = 0; c < DFEAT; ++c) x[3 + c] = pb[c];
    } else {
        const float* pb = pts + (size_t)b * DFEAT * NPTS + p;
#pragma unroll
        for (int c = 0; c < DFEAT; ++c) x[3 + c] = pb[(size_t)c * NPTS];
    }

    // layer 1: 67 -> 64
    for (int o = 0; o < C1; ++o) {
        float acc = 0.f;
#pragma unroll
        for (int c = 0; c < CIN; ++c) acc = fmaf(w0[o * CIN + c], x[c], acc);
        float sc = g0[o] * rsqrtf(rv0[o] + BN_EPS);
        float y = fmaf(sc, acc + b0[o] - rm0[o], bt0[o]);
        ylds[o][t] = fmaxf(y, 0.f);
    }
    __syncthreads();
    float x1[C1];
#pragma unroll
    for (int c = 0; c < C1; ++c) x1[c] = ylds[c][t];
    __syncthreads();

    // layer 2: 64 -> 64
    for (int o = 0; o < C2; ++o) {
        float acc = 0.f;
#pragma unroll
        for (int c = 0; c < C1; ++c) acc = fmaf(w1[o * C1 + c], x1[c], acc);
        float sc = g1[o] * rsqrtf(rv1[o] + BN_EPS);
        float y = fmaf(sc, acc + b1[o] - rm1[o], bt1[o]);
        ylds[o][t] = fmaxf(y, 0.f);
    }
    __syncthreads();
    float x2[C2];
#pragma unroll
    for (int c = 0; c < C2; ++c) x2[c] = ylds[c][t];

    // layer 3: 64 -> 128, then max over k (32 lanes sharing s)
    float* ob = outf + (size_t)b * C3 * NPOINT;
    for (int o = 0; o < C3; ++o) {
        float acc = 0.f;
#pragma unroll
        for (int c = 0; c < C2; ++c) acc = fmaf(w2[o * C2 + c], x2[c], acc);
        float sc = g2[o] * rsqrtf(rv2[o] + BN_EPS);
        float y = fmaf(sc, acc + b2[o] - rm2[o], bt2[o]);
        float v = fmaxf(y, 0.f);
#pragma unroll
        for (int m = 16; m >= 1; m >>= 1) v = fmaxf(v, __shfl_xor(v, m, 32));
        if (k == 0) ob[(size_t)o * NPOINT + s] = v;
    }
}

// ---------------------------------------------------------------------------
extern "C" void kernel_launch(void* const* d_in, const int* in_sizes, int n_in,
                              void* d_out, int out_size, void* d_ws, size_t ws_size,
                              hipStream_t stream) {
    const float* xyz = (const float*)d_in[0];
    const float* pts = (const float*)d_in[1];
    const float* w0 = (const float*)d_in[2];
    const float* b0 = (const float*)d_in[3];
    const float* g0 = (const float*)d_in[4];
    const float* bt0 = (const float*)d_in[5];
    const float* rm0 = (const float*)d_in[6];
    const float* rv0 = (const float*)d_in[7];
    const float* w1 = (const float*)d_in[8];
    const float* b1 = (const float*)d_in[9];
    const float* g1 = (const float*)d_in[10];
    const float* bt1 = (const float*)d_in[11];
    const float* rm1 = (const float*)d_in[12];
    const float* rv1 = (const float*)d_in[13];
    const float* w2 = (const float*)d_in[14];
    const float* b2 = (const float*)d_in[15];
    const float* g2 = (const float*)d_in[16];
    const float* bt2 = (const float*)d_in[17];
    const float* rm2 = (const float*)d_in[18];
    const float* rv2 = (const float*)d_in[19];

    float* out = (float*)d_out;
    float* outf = out + (size_t)BATCH * 3 * NPOINT;

    const size_t idx_bytes = (size_t)BATCH * NPOINT * NSAMPLE * sizeof(int);  // 1 MB
    const size_t idx_pad = (idx_bytes + 255) & ~(size_t)255;
    const size_t ptsT_bytes = (size_t)BATCH * NPTS * DFEAT * sizeof(float);   // 8 MB
    int* idx = (int*)d_ws;
    float* ptsT = (float*)((char*)d_ws + idx_pad);
    const bool useT = ws_size >= idx_pad + ptsT_bytes;

    fps_kernel<<<BATCH, 512, 0, stream>>>(xyz, out);
    if (useT) transpose_pts<<<BATCH * (NPTS / 64), 256, 0, stream>>>(pts, ptsT);
    ballquery_kernel<<<BATCH * NPOINT / 4, 256, 0, stream>>>(xyz, out, idx);
    if (useT) {
        mlp_kernel<1><<<BATCH * NPOINT / 8, 256, 0, stream>>>(
            xyz, ptsT, idx, out, w0, b0, g0, bt0, rm0, rv0, w1, b1, g1, bt1, rm1,
            rv1, w2, b2, g2, bt2, rm2, rv2, outf);
    } else {
        mlp_kernel<0><<<BATCH * NPOINT / 8, 256, 0, stream>>>(
            xyz, pts, idx, out, w0, b0, g0, bt0, rm0, rv0, w1, b1, g1, bt1, rm1,
            rv1, w2, b2, g2, bt2, rm2, rv2, outf);
    }
}